// Round 18
// baseline (723.770 us; speedup 1.0000x reference)
//
#include <hip/hip_runtime.h>

using bf16x8 = __attribute__((ext_vector_type(8))) short;
using f32x4  = __attribute__((ext_vector_type(4))) float;
using us4    = __attribute__((ext_vector_type(4))) unsigned short;

static __device__ __forceinline__ unsigned short f2bf(float x) {
  union { float f; unsigned u; } v; v.f = x;
  unsigned r = v.u + 0x7FFFu + ((v.u >> 16) & 1u);
  return (unsigned short)(r >> 16);
}
static __device__ __forceinline__ unsigned pack2bf(float a, float b) {
  return (unsigned)f2bf(a) | ((unsigned)f2bf(b) << 16);
}
static __device__ __forceinline__ void gload16(const unsigned short* g, unsigned short* lds_base) {
  __builtin_amdgcn_global_load_lds(
      (const __attribute__((address_space(1))) unsigned int*)g,
      (__attribute__((address_space(3))) unsigned int*)lds_base, 16, 0, 0);
}

// static softmax max: p = exp(s*0.125 - 10) computed as exp2(s*0.125*log2e - 10*log2e)
#define SCALE_L2E 0.18033688011112042f
#define M0_L2E    14.426950408889634f

// ---------- fused prep: cvt3 (9472 blk) + weight transposes (7168 blk) + bias2a (128 blk) ----------
__global__ __launch_bounds__(256) void k_prep(
    const float* __restrict__ x, const float* __restrict__ sq, const float* __restrict__ cw,
    unsigned short* __restrict__ xb, unsigned short* __restrict__ sqb,
    unsigned short* __restrict__ cwb,
    const float* __restrict__ cq, const float* __restrict__ ck, const float* __restrict__ cv,
    const float* __restrict__ lo, const float* __restrict__ qkv,
    unsigned short* __restrict__ wqt, unsigned short* __restrict__ wkvt,
    unsigned short* __restrict__ wlot, unsigned short* __restrict__ wqkvt,
    const float* __restrict__ qkv_w, const float* __restrict__ co_b,
    float* __restrict__ part) {
  __shared__ float tile[32][33];
  int id = blockIdx.x;
  const int t = threadIdx.x;
  if (id < 9472) {  // ---- f32 -> bf16 converts ----
    const float* in; unsigned short* out; int i;
    if (id < 8192)      { in = x;  out = xb;  i = id * 256 + t; }
    else if (id < 8448) { in = sq; out = sqb; i = (id - 8192) * 256 + t; }
    else                { in = cw; out = cwb; i = (id - 8448) * 256 + t; }
    float4 v = ((const float4*)in)[i];
    us4 o = { f2bf(v.x), f2bf(v.y), f2bf(v.z), f2bf(v.w) };
    ((us4*)out)[i] = o;
  } else if (id < 16640) {  // ---- weight transposes: W (1024,N) f32 -> Wt (N,1024) bf16 ----
    id -= 9472;
    const float* W; unsigned short* Wt; int N;
    if (id < 1024)      { W = cq;  Wt = wqt;                N = 1024; }
    else if (id < 2048) { W = ck;  Wt = wkvt;               N = 1024; id -= 1024; }
    else if (id < 3072) { W = cv;  Wt = wkvt + 1024 * 1024; N = 1024; id -= 2048; }
    else if (id < 4096) { W = lo;  Wt = wlot;               N = 1024; id -= 3072; }
    else                { W = qkv; Wt = wqkvt;              N = 3072; id -= 4096; }
    int ntb = N >> 5;
    int nb = (id % ntb) * 32, kb = (id / ntb) * 32;
    int k = t >> 3, n4 = (t & 7) << 2;
    float4 v = *(const float4*)&W[(size_t)(kb + k) * N + nb + n4];
    tile[k][n4] = v.x; tile[k][n4 + 1] = v.y; tile[k][n4 + 2] = v.z; tile[k][n4 + 3] = v.w;
    __syncthreads();
    int n = t >> 3, k4 = (t & 7) << 2;
    us4 o = { f2bf(tile[k4][n]), f2bf(tile[k4 + 1][n]), f2bf(tile[k4 + 2][n]), f2bf(tile[k4 + 3][n]) };
    *(us4*)&Wt[(size_t)(nb + n) * 1024 + kb + k4] = o;
  } else {  // ---- bias2 stage A: partial sums over 64-j slices ----
    id -= 16640;
    int nb = id & 7, jb = id >> 3;
    int n = nb * 256 + t;
    float s = 0.f;
    int j0 = jb * 64;
#pragma unroll 4
    for (int j = j0; j < j0 + 64; ++j) s += co_b[j] * qkv_w[(size_t)j * 3072 + 1024 + n];
    part[jb * 2048 + n] = s;
  }
}

// ---------- bias2 stage B + kvb/zbias fill ----------
__global__ __launch_bounds__(256) void k_bias2b(const float* __restrict__ part,
                                                const float* __restrict__ qkv_b,
                                                const float* __restrict__ ck_b,
                                                const float* __restrict__ cv_b,
                                                float* __restrict__ bias2,
                                                float* __restrict__ kvb,
                                                float* __restrict__ zbias) {
  int id = blockIdx.x, t = threadIdx.x;
  if (id < 8) {
    int n = id * 256 + t;
    float s = qkv_b[1024 + n];
#pragma unroll
    for (int jb = 0; jb < 16; ++jb) s += part[jb * 2048 + n];
    bias2[n] = s;
  } else {
    for (int j = t; j < 1024; j += 256) {
      kvb[j] = ck_b[j]; kvb[1024 + j] = cv_b[j]; zbias[j] = 0.f;
    }
  }
}

// ---------- GEMM: C = A(M,K)bf16 @ Bt(N,K)^T + bias ----------
// NSTAGE LDS pipeline (r12) + T2 XOR swizzle (r13: conflicts 6.29M->0) + BM=256
// (r14: big qkv 75.6->62.9us). NO XCD block swizzle (r16: default order already optimal).
template <int BM, int NSTAGE = (BM == 256 ? 2 : 3)>
__global__ __launch_bounds__(BM * 2) void k_gemm(
    const unsigned short* __restrict__ A, long long bsA, int Lr,
    const unsigned short* __restrict__ Bt, const float* __restrict__ bias,
    unsigned short* __restrict__ outb, int Nout,
    unsigned short* __restrict__ outb2,
    unsigned short* __restrict__ outT, int Lv, int vt_col0,
    const float* __restrict__ resx, float* __restrict__ resout,
    unsigned short* __restrict__ rescob, int chunk,
    int N, int K) {
  constexpr int NWAVES = (BM * 2) / 64;
  constexpr int NA = BM / 16;
  constexpr int NINST = NA + 8;
  constexpr int NPW = NINST / NWAVES;
  static_assert(NPW * NWAVES == NINST, "staging split");
  constexpr int STRIDE = (BM + 128) * 32;
  __shared__ unsigned short Ls[NSTAGE * STRIDE];
  const int m0 = blockIdx.x * BM, n0 = blockIdx.y * 128;
  const int t = threadIdx.x, w = t >> 6, l = t & 63;
  const int wr = (BM == 64) ? 0 : (w >> 1);
  const int wc = (BM == 64) ? w : (w & 1);
  const int lg = l >> 4, lq = l & 15;
  const int batch = m0 / Lr, mrow = m0 % Lr;
  const int srow = l >> 2;
  const int scol = (((l & 3) ^ ((l >> 3) & 3)) << 3);   // swizzled global source col
  const unsigned short* gp[NPW];
  int lofs[NPW];
#pragma unroll
  for (int jj = 0; jj < NPW; ++jj) {
    int j = w * NPW + jj;
    if (j < NA) {
      int r = mrow + j * 16 + srow;
      gp[jj] = A + (size_t)batch * (size_t)bsA + (size_t)r * K + scol;
      lofs[jj] = j * 512;
    } else {
      int r = n0 + (j - NA) * 16 + srow;
      gp[jj] = Bt + (size_t)r * K + scol;
      lofs[jj] = BM * 32 + (j - NA) * 512;
    }
  }
  const int lsw = (lg ^ ((lq >> 1) & 3)) * 8;   // swizzled read slot
  const f32x4 fz = {0.f, 0.f, 0.f, 0.f};
  f32x4 acc[4][4];
#pragma unroll
  for (int i = 0; i < 4; ++i)
#pragma unroll
    for (int j = 0; j < 4; ++j) acc[i][j] = fz;
  const int nsteps = K >> 5;
#pragma unroll
  for (int st = 0; st < NSTAGE - 1; ++st) {
    if (st < nsteps) {
#pragma unroll
      for (int jj = 0; jj < NPW; ++jj) gload16(gp[jj] + (st << 5), &Ls[st * STRIDE + lofs[jj]]);
    }
  }
  int cur = 0;
  int nxt = (NSTAGE - 1) * STRIDE;
  for (int s = 0; s < nsteps; ++s) {
    if (s + NSTAGE - 1 < nsteps) {
      const int kk = (s + NSTAGE - 1) << 5;
#pragma unroll
      for (int jj = 0; jj < NPW; ++jj) gload16(gp[jj] + kk, &Ls[nxt + lofs[jj]]);
      asm volatile("s_waitcnt vmcnt(%0)" :: "n"((NSTAGE - 1) * NPW) : "memory");
    } else if (NSTAGE >= 3 && s + 1 < nsteps) {
      asm volatile("s_waitcnt vmcnt(%0)" :: "n"(NPW) : "memory");
    } else {
      asm volatile("s_waitcnt vmcnt(0)" ::: "memory");
    }
    __builtin_amdgcn_s_barrier();
    bf16x8 af[4], bg[4];
#pragma unroll
    for (int i = 0; i < 4; ++i) {
      af[i] = *(const bf16x8*)&Ls[cur + (wr * 64 + i * 16 + lq) * 32 + lsw];
      bg[i] = *(const bf16x8*)&Ls[cur + BM * 32 + (wc * 64 + i * 16 + lq) * 32 + lsw];
    }
#pragma unroll
    for (int i = 0; i < 4; ++i)
#pragma unroll
      for (int j = 0; j < 4; ++j)
        acc[i][j] = __builtin_amdgcn_mfma_f32_16x16x32_bf16(af[i], bg[j], acc[i][j], 0, 0, 0);
    __builtin_amdgcn_s_barrier();
    cur += STRIDE; if (cur == NSTAGE * STRIDE) cur = 0;
    nxt += STRIDE; if (nxt == NSTAGE * STRIDE) nxt = 0;
  }
  const int lr = lg << 2;
#pragma unroll
  for (int i = 0; i < 4; ++i) {
    const int rowb = m0 + wr * 64 + i * 16 + lr;
#pragma unroll
    for (int j = 0; j < 4; ++j) {
      const int col = n0 + wc * 64 + j * 16 + lq;
      const float bv = bias[col];
      float v0 = acc[i][j][0] + bv, v1 = acc[i][j][1] + bv;
      float v2 = acc[i][j][2] + bv, v3 = acc[i][j][3] + bv;
      if (outT && col >= vt_col0) {
        const int vc = col - vt_col0;
        const int hh = vc >> 6, dd = vc & 63;
        const int bb = rowb / Lr, key = rowb % Lr;
        us4 o = { f2bf(v0), f2bf(v1), f2bf(v2), f2bf(v3) };
        *(us4*)&outT[((size_t)((bb << 4) + hh) * 64 + dd) * Lv + key] = o;
      } else if (outb2 && col >= 1024) {
        const int c2 = col - 1024;
        outb2[(size_t)(rowb + 0) * 1024 + c2] = f2bf(v0);
        outb2[(size_t)(rowb + 1) * 1024 + c2] = f2bf(v1);
        outb2[(size_t)(rowb + 2) * 1024 + c2] = f2bf(v2);
        outb2[(size_t)(rowb + 3) * 1024 + c2] = f2bf(v3);
      } else if (resx) {
        const int bb = rowb / Lr, r = rowb % Lr;
        const size_t xo = ((size_t)(bb * 4096 + chunk * 1024 + r)) * 1024 + col;
        const size_t co = ((size_t)(bb * 1024 + r)) * 1024 + col;
        float r0 = v0 + resx[xo];
        float r1 = v1 + resx[xo + 1024];
        float r2 = v2 + resx[xo + 2048];
        float r3 = v3 + resx[xo + 3072];
        resout[xo] = r0; resout[xo + 1024] = r1;
        resout[xo + 2048] = r2; resout[xo + 3072] = r3;
        rescob[co] = f2bf(r0); rescob[co + 1024] = f2bf(r1);
        rescob[co + 2048] = f2bf(r2); rescob[co + 3072] = f2bf(r3);
      } else {
        outb[(size_t)(rowb + 0) * Nout + col] = f2bf(v0);
        outb[(size_t)(rowb + 1) * Nout + col] = f2bf(v1);
        outb[(size_t)(rowb + 2) * Nout + col] = f2bf(v2);
        outb[(size_t)(rowb + 3) * Nout + col] = f2bf(v3);
      }
    }
  }
}

// ================= flash attention: LDS-staged, r14-proven (two barriers, 27.6KB) ========
// MODE 1: causal over chunk keys -> f32 partials (l, acc); grid packs 4 chunks, LPT.
// MODE 3: comp attn, 4-way split-K -> f32 partials; LAST split block per (bh,qg)
//         merges all 4 splits -> attc (device-scope fence + atomic counter; removes k_fam).
// MODE 2: resume chunk partials, add 256 gctx keys -> normalized O bf16.
template <int MODE>
__global__ __launch_bounds__(256) void k_fa(
    const unsigned short* __restrict__ Q, long long q_bs, int q_stride, int q_row0,
    const unsigned short* __restrict__ K, long long k_bs, int k_stride,
    const unsigned short* __restrict__ V, int Lk,
    unsigned short* __restrict__ O, int Lq_out,
    float* __restrict__ pl, float* __restrict__ pacc, int* __restrict__ cnt) {
  __shared__ unsigned short Ks[64 * 72];
  __shared__ unsigned short Vs[64 * 72];
  __shared__ unsigned short Ps[4 * 16 * 72];
  __shared__ int mflag;
  const int t = threadIdx.x, w = t >> 6, l = t & 63;
  const int lg = l >> 4, lq = l & 15;
  const int bh = blockIdx.x & 31;
  const int rest = blockIdx.x >> 5;
  const int b = bh >> 4, h = bh & 15;
  int qg, koff, ntiles;
  if (MODE == 1)      { qg = 15 - (rest & 15); koff = (rest >> 4) << 10; ntiles = qg + 1; }
  else if (MODE == 3) { qg = rest & 3;         koff = (rest >> 2) << 8;  ntiles = 4; }
  else                { qg = rest;             koff = 0;                 ntiles = 4; }
  const int qloc = qg * 64 + w * 16 + lq;
  const int qglob = q_row0 + (MODE == 1 ? koff : 0) + qloc;
  const unsigned short* qp = Q + (size_t)b * (size_t)q_bs + (size_t)qglob * q_stride + h * 64;
  bf16x8 qf0 = *(const bf16x8*)&qp[lg * 8];
  bf16x8 qf1 = *(const bf16x8*)&qp[32 + lg * 8];
  const f32x4 fz = {0.f, 0.f, 0.f, 0.f};
  const int pidx = (MODE == 2 ? 0 : (koff << 5)) + bh * (MODE == 3 ? 256 : 1024) + qloc;
  f32x4 acc0, acc1, acc2, acc3;
  float lbase = 0.f;
  if (MODE == 2) {
    lbase = pl[pidx];
    const float* pb = &pacc[(size_t)pidx * 64];
    float4 a0 = *(const float4*)&pb[0 * 16 + lg * 4];
    float4 a1 = *(const float4*)&pb[1 * 16 + lg * 4];
    float4 a2 = *(const float4*)&pb[2 * 16 + lg * 4];
    float4 a3 = *(const float4*)&pb[3 * 16 + lg * 4];
    acc0[0] = a0.x; acc0[1] = a0.y; acc0[2] = a0.z; acc0[3] = a0.w;
    acc1[0] = a1.x; acc1[1] = a1.y; acc1[2] = a1.z; acc1[3] = a1.w;
    acc2[0] = a2.x; acc2[1] = a2.y; acc2[2] = a2.z; acc2[3] = a2.w;
    acc3[0] = a3.x; acc3[1] = a3.y; acc3[2] = a3.z; acc3[3] = a3.w;
  } else {
    acc0 = fz; acc1 = fz; acc2 = fz; acc3 = fz;
  }
  float psum = 0.f;
  const int sr = t >> 2, sc = (t & 3) << 4;
  const unsigned short* kbp = K + (size_t)b * (size_t)k_bs + (size_t)koff * k_stride + h * 64;
  const unsigned short* vbp = V + (size_t)(((b << 4) + h) * 64) * Lk + koff;
  unsigned short* pw = &Ps[(w * 16 + lq) * 72];
  bf16x8 kr0, kr1, vr0, vr1;
  {
    const unsigned short* kp = kbp + (size_t)sr * k_stride + sc;
    kr0 = *(const bf16x8*)kp; kr1 = *(const bf16x8*)(kp + 8);
    const unsigned short* vp = vbp + (size_t)sr * Lk + sc;
    vr0 = *(const bf16x8*)vp; vr1 = *(const bf16x8*)(vp + 8);
  }
#define KFA_SM(Z, KH) do { \
    float e0_ = Z[0] * SCALE_L2E - M0_L2E; \
    float e1_ = Z[1] * SCALE_L2E - M0_L2E; \
    float e2_ = Z[2] * SCALE_L2E - M0_L2E; \
    float e3_ = Z[3] * SCALE_L2E - M0_L2E; \
    if (MODE == 1) { \
      int kg_ = k0 + (KH) * 16 + lg * 4; \
      if (kg_ + 0 > qloc) e0_ = -1e9f; \
      if (kg_ + 1 > qloc) e1_ = -1e9f; \
      if (kg_ + 2 > qloc) e2_ = -1e9f; \
      if (kg_ + 3 > qloc) e3_ = -1e9f; \
    } \
    float p0_ = exp2f(e0_), p1_ = exp2f(e1_), p2_ = exp2f(e2_), p3_ = exp2f(e3_); \
    psum += (p0_ + p1_) + (p2_ + p3_); \
    *(unsigned*)&pw[(KH) * 16 + lg * 4]     = pack2bf(p0_, p1_); \
    *(unsigned*)&pw[(KH) * 16 + lg * 4 + 2] = pack2bf(p2_, p3_); \
  } while (0)
#define KFA_MFMA(A_, B_, C_) __builtin_amdgcn_mfma_f32_16x16x32_bf16(A_, B_, C_, 0, 0, 0)
  for (int kt = 0; kt < ntiles; ++kt) {
    const int k0 = kt * 64;
    __syncthreads();
    *(bf16x8*)&Ks[sr * 72 + sc] = kr0; *(bf16x8*)&Ks[sr * 72 + sc + 8] = kr1;
    *(bf16x8*)&Vs[sr * 72 + sc] = vr0; *(bf16x8*)&Vs[sr * 72 + sc + 8] = vr1;
    __syncthreads();
    if (kt + 1 < ntiles) {
      const unsigned short* kp = kbp + (size_t)(k0 + 64 + sr) * k_stride + sc;
      kr0 = *(const bf16x8*)kp; kr1 = *(const bf16x8*)(kp + 8);
      const unsigned short* vp = vbp + (size_t)sr * Lk + k0 + 64 + sc;
      vr0 = *(const bf16x8*)vp; vr1 = *(const bf16x8*)(vp + 8);
    }
    f32x4 z0 = fz, z1 = fz, z2 = fz, z3 = fz;
    __builtin_amdgcn_s_setprio(1);
    z0 = KFA_MFMA(*(const bf16x8*)&Ks[(0 * 16 + lq) * 72 + lg * 8], qf0, z0);
    z1 = KFA_MFMA(*(const bf16x8*)&Ks[(1 * 16 + lq) * 72 + lg * 8], qf0, z1);
    z2 = KFA_MFMA(*(const bf16x8*)&Ks[(2 * 16 + lq) * 72 + lg * 8], qf0, z2);
    z3 = KFA_MFMA(*(const bf16x8*)&Ks[(3 * 16 + lq) * 72 + lg * 8], qf0, z3);
    z0 = KFA_MFMA(*(const bf16x8*)&Ks[(0 * 16 + lq) * 72 + 32 + lg * 8], qf1, z0);
    z1 = KFA_MFMA(*(const bf16x8*)&Ks[(1 * 16 + lq) * 72 + 32 + lg * 8], qf1, z1);
    z2 = KFA_MFMA(*(const bf16x8*)&Ks[(2 * 16 + lq) * 72 + 32 + lg * 8], qf1, z2);
    z3 = KFA_MFMA(*(const bf16x8*)&Ks[(3 * 16 + lq) * 72 + 32 + lg * 8], qf1, z3);
    __builtin_amdgcn_s_setprio(0);
    KFA_SM(z0, 0); KFA_SM(z1, 1); KFA_SM(z2, 2); KFA_SM(z3, 3);
    asm volatile("s_waitcnt lgkmcnt(0)" ::: "memory");
    __builtin_amdgcn_sched_barrier(0);
    bf16x8 pf0 = *(const bf16x8*)&pw[lg * 8];
    bf16x8 pf1 = *(const bf16x8*)&pw[32 + lg * 8];
    asm volatile("" ::: "memory");
    __builtin_amdgcn_sched_barrier(0);
    __builtin_amdgcn_s_setprio(1);
    acc0 = KFA_MFMA(*(const bf16x8*)&Vs[(0 * 16 + lq) * 72 + lg * 8], pf0, acc0);
    acc1 = KFA_MFMA(*(const bf16x8*)&Vs[(1 * 16 + lq) * 72 + lg * 8], pf0, acc1);
    acc2 = KFA_MFMA(*(const bf16x8*)&Vs[(2 * 16 + lq) * 72 + lg * 8], pf0, acc2);
    acc3 = KFA_MFMA(*(const bf16x8*)&Vs[(3 * 16 + lq) * 72 + lg * 8], pf0, acc3);
    acc0 = KFA_MFMA(*(const bf16x8*)&Vs[(0 * 16 + lq) * 72 + 32 + lg * 8], pf1, acc0);
    acc1 = KFA_MFMA(*(const bf16x8*)&Vs[(1 * 16 + lq) * 72 + 32 + lg * 8], pf1, acc1);
    acc2 = KFA_MFMA(*(const bf16x8*)&Vs[(2 * 16 + lq) * 72 + 32 + lg * 8], pf1, acc2);
    acc3 = KFA_MFMA(*(const bf16x8*)&Vs[(3 * 16 + lq) * 72 + 32 + lg * 8], pf1, acc3);
    __builtin_amdgcn_s_setprio(0);
  }
#undef KFA_SM
#undef KFA_MFMA
  psum += __shfl_xor(psum, 16);
  psum += __shfl_xor(psum, 32);
  if (MODE == 2) {
    float inv = 1.f / (lbase + psum);
    size_t ob = ((size_t)b * Lq_out + qloc) * 1024 + h * 64;
    us4 o0 = { f2bf(acc0[0] * inv), f2bf(acc0[1] * inv), f2bf(acc0[2] * inv), f2bf(acc0[3] * inv) };
    us4 o1 = { f2bf(acc1[0] * inv), f2bf(acc1[1] * inv), f2bf(acc1[2] * inv), f2bf(acc1[3] * inv) };
    us4 o2 = { f2bf(acc2[0] * inv), f2bf(acc2[1] * inv), f2bf(acc2[2] * inv), f2bf(acc2[3] * inv) };
    us4 o3 = { f2bf(acc3[0] * inv), f2bf(acc3[1] * inv), f2bf(acc3[2] * inv), f2bf(acc3[3] * inv) };
    *(us4*)&O[ob + 0 * 16 + lg * 4] = o0;
    *(us4*)&O[ob + 1 * 16 + lg * 4] = o1;
    *(us4*)&O[ob + 2 * 16 + lg * 4] = o2;
    *(us4*)&O[ob + 3 * 16 + lg * 4] = o3;
  } else {
    if (lg == 0) pl[pidx] = psum;
    float* pb = &pacc[(size_t)pidx * 64];
    *(float4*)&pb[0 * 16 + lg * 4] = make_float4(acc0[0], acc0[1], acc0[2], acc0[3]);
    *(float4*)&pb[1 * 16 + lg * 4] = make_float4(acc1[0], acc1[1], acc1[2], acc1[3]);
    *(float4*)&pb[2 * 16 + lg * 4] = make_float4(acc2[0], acc2[1], acc2[2], acc2[3]);
    *(float4*)&pb[3 * 16 + lg * 4] = make_float4(acc3[0], acc3[1], acc3[2], acc3[3]);
    if (MODE == 3) {
      // last split block per (bh,qg) merges the 4 splits -> attc (in O)
      __threadfence();                              // release: partials visible device-wide
      if (t == 0) mflag = atomicAdd(&cnt[bh * 4 + qg], 1);
      __syncthreads();
      if (mflag == 3) {
        __threadfence();                            // acquire: see other splits' partials
        for (int it = t; it < 1024; it += 256) {
          const int r = it >> 4, d4 = (it & 15) << 2;
          const int row = bh * 256 + qg * 64 + r;
          float lsum = 0.f;
          float4 o = make_float4(0.f, 0.f, 0.f, 0.f);
#pragma unroll
          for (int s = 0; s < 4; ++s) {
            lsum += pl[s * 8192 + row];
            float4 a = *(const float4*)&pacc[((size_t)(s * 8192 + row)) * 64 + d4];
            o.x += a.x; o.y += a.y; o.z += a.z; o.w += a.w;
          }
          float inv = 1.f / lsum;
          const int q = qg * 64 + r;
          us4 ov = { f2bf(o.x * inv), f2bf(o.y * inv), f2bf(o.z * inv), f2bf(o.w * inv) };
          *(us4*)&O[((size_t)(b * 256 + q)) * 1024 + h * 64 + d4] = ov;
        }
      }
    }
  }
}

extern "C" void kernel_launch(void* const* d_in, const int* in_sizes, int n_in,
                              void* d_out, int out_size, void* d_ws, size_t ws_size,
                              hipStream_t stream) {
  const float* x     = (const float*)d_in[0];
  const float* sq    = (const float*)d_in[1];
  const float* cq_w  = (const float*)d_in[2];
  const float* cq_b  = (const float*)d_in[3];
  const float* ck_w  = (const float*)d_in[4];
  const float* ck_b  = (const float*)d_in[5];
  const float* cv_w  = (const float*)d_in[6];
  const float* cv_b  = (const float*)d_in[7];
  const float* co_w  = (const float*)d_in[8];
  const float* co_b  = (const float*)d_in[9];
  const float* qkv_w = (const float*)d_in[10];
  const float* qkv_b = (const float*)d_in[11];
  const float* lo_w  = (const float*)d_in[12];
  const float* lo_b  = (const float*)d_in[13];
  float* out = (float*)d_out;

  char* ws = (char*)d_ws;
  size_t off = 0;
  auto alloc = [&](size_t bytes) -> void* {
    void* p = ws + off;
    off += (bytes + 255) & ~(size_t)255;
    return p;
  };
  unsigned short* xb    = (unsigned short*)alloc(16777216);  // x bf16 (B,4096,1024)
  unsigned short* sqb   = (unsigned short*)alloc(524288);
  unsigned short* cow16 = (unsigned short*)alloc(2097152);   // co_w bf16 row-major
  unsigned short* wqt   = (unsigned short*)alloc(2097152);
  unsigned short* wkvt  = (unsigned short*)alloc(4194304);   // [ck^T ; cv^T]
  unsigned short* wlot  = (unsigned short*)alloc(2097152);
  unsigned short* wqkvt = (unsigned short*)alloc(6291456);   // qkv^T (3072,1024)
  unsigned short* w2t   = (unsigned short*)alloc(4194304);   // (co_w @ qkv_w[:,1024:])^T
  float*          bias2 = (float*)alloc(8192);
  float*          kvb   = (float*)alloc(8192);
  float*          zbias = (float*)alloc(4096);
  float*          part  = (float*)alloc(131072);
  unsigned short* qs    = (unsigned short*)alloc(524288);    // summary q (256,1024)
  unsigned short* qx    = (unsigned short*)alloc(16777216);  // Q of x (B,4096,1024)
  unsigned short* kx    = (unsigned short*)alloc(16777216);  // K of x (B,4096,1024)
  unsigned short* vtx   = (unsigned short*)alloc(16777216);  // V^T of x (B,16,64,4096)
  unsigned short* gk    = (unsigned short*)alloc(1048576);   // gctx K (B,256,1024)
  unsigned short* gvt   = (unsigned short*)alloc(1048576);   // gctx V^T (B,16,64,256)
  unsigned short* kc    = (unsigned short*)alloc(4194304);   // comp K (B,1024,1024)
  unsigned short* vtc   = (unsigned short*)alloc(4194304);   // comp V^T (B,16,64,1024)
  unsigned short* attc  = (unsigned short*)alloc(1048576);   // comp attn out (B,256,1024)
  unsigned short* attl  = (unsigned short*)alloc(4194304);   // local attn out (B,1024,1024)
  unsigned short* cob   = (unsigned short*)alloc(4194304);   // chunk_out bf16
  float*          plb   = (float*)alloc(524288);             // (4,B,16,1024) l partials
  float*          pacc  = (float*)alloc(33554432);           // (4,B,16,1024,64) acc partials
  float*          pl0   = (float*)alloc(131072);             // (4,B,16,256) comp split-K l
  float*          pacc0 = (float*)alloc(8388608);            // (4,B,16,256,64) comp split-K acc
  int*            cnt   = (int*)alloc(4 * 128 * sizeof(int)); // merge counters, 4 comp calls

  hipMemsetAsync(cnt, 0, 4 * 128 * sizeof(int), stream);

  // ---- prep (one fused dispatch) ----
  k_prep<<<16768, 256, 0, stream>>>(x, sq, co_w, xb, sqb, cow16,
                                    cq_w, ck_w, cv_w, lo_w, qkv_w,
                                    wqt, wkvt, wlot, wqkvt,
                                    qkv_w, co_b, part);
  k_bias2b<<<9, 256, 0, stream>>>(part, qkv_b, ck_b, cv_b, bias2, kvb, zbias);
  // q_summary
  k_gemm<64><<<dim3(4, 8), 128, 0, stream>>>(sqb, 0, 256, wqt, cq_b, qs, 1024, nullptr,
                                             nullptr, 0, 0, nullptr, nullptr, nullptr, 0, 1024, 1024);
  // W2^T
  k_gemm<128><<<dim3(16, 8), 256, 0, stream>>>(wqkvt + 1024 * 1024, 0, 2048, cow16, zbias,
                                               w2t, 1024, nullptr, nullptr, 0, 0,
                                               nullptr, nullptr, nullptr, 0, 1024, 1024);
  // big qkv projection: Q->qx, K->kx, V->vtx (BM=256: 768 blocks, 3/CU resident)
  k_gemm<256><<<dim3(32, 24), 512, 0, stream>>>(xb, 4096LL * 1024, 4096, wqkvt, qkv_b,
                                                qx, 1024, kx, vtx, 4096, 2048,
                                                nullptr, nullptr, nullptr, 0, 3072, 1024);
  // causal partials for ALL chunks (LPT-ordered grid)
  k_fa<1><<<2048, 256, 0, stream>>>(qx, 4096LL * 1024, 1024, 0,
                                    kx, 4096LL * 1024, 1024,
                                    vtx, 4096, nullptr, 0, plb, pacc, nullptr);

  int compCall = 0;
  auto comp = [&](const unsigned short* inA, long long bsA) {
    k_gemm<64><<<dim3(32, 16), 128, 0, stream>>>(inA, bsA, 1024, wkvt, kvb,
                                                 kc, 1024, nullptr, vtc, 1024, 1024,
                                                 nullptr, nullptr, nullptr, 0, 2048, 1024);
    k_fa<3><<<512, 256, 0, stream>>>(qs, 0LL, 1024, 0,
                                     kc, 1024LL * 1024, 1024,
                                     vtc, 1024, attc, 256, pl0, pacc0,
                                     cnt + compCall * 128);
    ++compCall;
    k_gemm<64><<<dim3(8, 16), 128, 0, stream>>>(attc, 256LL * 1024, 256, w2t, bias2,
                                                gk, 1024, nullptr, gvt, 256, 1024,
                                                nullptr, nullptr, nullptr, 0, 2048, 1024);
  };

  comp(xb, 4096LL * 1024);  // gctx_0 from raw chunk 0
  for (int i = 0; i < 4; ++i) {
    k_fa<2><<<512, 256, 0, stream>>>(qx, 4096LL * 1024, 1024, i * 1024,
                                     gk, 256LL * 1024, 1024,
                                     gvt, 256, attl, 1024,
                                     plb + (size_t)i * 32768, pacc + (size_t)i * 32768 * 64,
                                     nullptr);
    k_gemm<64><<<dim3(32, 8), 128, 0, stream>>>(attl, 1024LL * 1024, 1024, wlot, lo_b,
                                                nullptr, 1024, nullptr, nullptr, 0, 0,
                                                x, out, cob, i, 1024, 1024);
    if (i < 3) comp(cob, 1024LL * 1024);
  }
}

// Round 19
// 469.905 us; speedup vs baseline: 1.5402x; 1.5402x over previous
//
#include <hip/hip_runtime.h>

using bf16x8 = __attribute__((ext_vector_type(8))) short;
using f32x4  = __attribute__((ext_vector_type(4))) float;
using us4    = __attribute__((ext_vector_type(4))) unsigned short;

static __device__ __forceinline__ unsigned short f2bf(float x) {
  union { float f; unsigned u; } v; v.f = x;
  unsigned r = v.u + 0x7FFFu + ((v.u >> 16) & 1u);
  return (unsigned short)(r >> 16);
}
static __device__ __forceinline__ unsigned pack2bf(float a, float b) {
  return (unsigned)f2bf(a) | ((unsigned)f2bf(b) << 16);
}
static __device__ __forceinline__ void gload16(const unsigned short* g, unsigned short* lds_base) {
  __builtin_amdgcn_global_load_lds(
      (const __attribute__((address_space(1))) unsigned int*)g,
      (__attribute__((address_space(3))) unsigned int*)lds_base, 16, 0, 0);
}

// static softmax max: p = exp(s*0.125 - 10) computed as exp2(s*0.125*log2e - 10*log2e)
#define SCALE_L2E 0.18033688011112042f
#define M0_L2E    14.426950408889634f

// ---------- fused prep: cvt3 (9472 blk) + weight transposes (7168 blk) + bias2a (128 blk) ----------
__global__ __launch_bounds__(256) void k_prep(
    const float* __restrict__ x, const float* __restrict__ sq, const float* __restrict__ cw,
    unsigned short* __restrict__ xb, unsigned short* __restrict__ sqb,
    unsigned short* __restrict__ cwb,
    const float* __restrict__ cq, const float* __restrict__ ck, const float* __restrict__ cv,
    const float* __restrict__ lo, const float* __restrict__ qkv,
    unsigned short* __restrict__ wqt, unsigned short* __restrict__ wkvt,
    unsigned short* __restrict__ wlot, unsigned short* __restrict__ wqkvt,
    const float* __restrict__ qkv_w, const float* __restrict__ co_b,
    float* __restrict__ part) {
  __shared__ float tile[32][33];
  int id = blockIdx.x;
  const int t = threadIdx.x;
  if (id < 9472) {  // ---- f32 -> bf16 converts ----
    const float* in; unsigned short* out; int i;
    if (id < 8192)      { in = x;  out = xb;  i = id * 256 + t; }
    else if (id < 8448) { in = sq; out = sqb; i = (id - 8192) * 256 + t; }
    else                { in = cw; out = cwb; i = (id - 8448) * 256 + t; }
    float4 v = ((const float4*)in)[i];
    us4 o = { f2bf(v.x), f2bf(v.y), f2bf(v.z), f2bf(v.w) };
    ((us4*)out)[i] = o;
  } else if (id < 16640) {  // ---- weight transposes: W (1024,N) f32 -> Wt (N,1024) bf16 ----
    id -= 9472;
    const float* W; unsigned short* Wt; int N;
    if (id < 1024)      { W = cq;  Wt = wqt;                N = 1024; }
    else if (id < 2048) { W = ck;  Wt = wkvt;               N = 1024; id -= 1024; }
    else if (id < 3072) { W = cv;  Wt = wkvt + 1024 * 1024; N = 1024; id -= 2048; }
    else if (id < 4096) { W = lo;  Wt = wlot;               N = 1024; id -= 3072; }
    else                { W = qkv; Wt = wqkvt;              N = 3072; id -= 4096; }
    int ntb = N >> 5;
    int nb = (id % ntb) * 32, kb = (id / ntb) * 32;
    int k = t >> 3, n4 = (t & 7) << 2;
    float4 v = *(const float4*)&W[(size_t)(kb + k) * N + nb + n4];
    tile[k][n4] = v.x; tile[k][n4 + 1] = v.y; tile[k][n4 + 2] = v.z; tile[k][n4 + 3] = v.w;
    __syncthreads();
    int n = t >> 3, k4 = (t & 7) << 2;
    us4 o = { f2bf(tile[k4][n]), f2bf(tile[k4 + 1][n]), f2bf(tile[k4 + 2][n]), f2bf(tile[k4 + 3][n]) };
    *(us4*)&Wt[(size_t)(nb + n) * 1024 + kb + k4] = o;
  } else {  // ---- bias2 stage A: partial sums over 64-j slices ----
    id -= 16640;
    int nb = id & 7, jb = id >> 3;
    int n = nb * 256 + t;
    float s = 0.f;
    int j0 = jb * 64;
#pragma unroll 4
    for (int j = j0; j < j0 + 64; ++j) s += co_b[j] * qkv_w[(size_t)j * 3072 + 1024 + n];
    part[jb * 2048 + n] = s;
  }
}

// ---------- bias2 stage B + kvb/zbias fill ----------
__global__ __launch_bounds__(256) void k_bias2b(const float* __restrict__ part,
                                                const float* __restrict__ qkv_b,
                                                const float* __restrict__ ck_b,
                                                const float* __restrict__ cv_b,
                                                float* __restrict__ bias2,
                                                float* __restrict__ kvb,
                                                float* __restrict__ zbias) {
  int id = blockIdx.x, t = threadIdx.x;
  if (id < 8) {
    int n = id * 256 + t;
    float s = qkv_b[1024 + n];
#pragma unroll
    for (int jb = 0; jb < 16; ++jb) s += part[jb * 2048 + n];
    bias2[n] = s;
  } else {
    for (int j = t; j < 1024; j += 256) {
      kvb[j] = ck_b[j]; kvb[1024 + j] = cv_b[j]; zbias[j] = 0.f;
    }
  }
}

// ---------- GEMM: C = A(M,K)bf16 @ Bt(N,K)^T + bias ----------
// NSTAGE LDS pipeline (r12) + T2 XOR swizzle (r13: conflicts 6.29M->0) + BM=256
// (r14: big qkv 75.6->62.9us). NO XCD block swizzle (r16: default order already optimal).
template <int BM, int NSTAGE = (BM == 256 ? 2 : 3)>
__global__ __launch_bounds__(BM * 2) void k_gemm(
    const unsigned short* __restrict__ A, long long bsA, int Lr,
    const unsigned short* __restrict__ Bt, const float* __restrict__ bias,
    unsigned short* __restrict__ outb, int Nout,
    unsigned short* __restrict__ outb2,
    unsigned short* __restrict__ outT, int Lv, int vt_col0,
    const float* __restrict__ resx, float* __restrict__ resout,
    unsigned short* __restrict__ rescob, int chunk,
    int N, int K) {
  constexpr int NWAVES = (BM * 2) / 64;
  constexpr int NA = BM / 16;
  constexpr int NINST = NA + 8;
  constexpr int NPW = NINST / NWAVES;
  static_assert(NPW * NWAVES == NINST, "staging split");
  constexpr int STRIDE = (BM + 128) * 32;
  __shared__ unsigned short Ls[NSTAGE * STRIDE];
  const int m0 = blockIdx.x * BM, n0 = blockIdx.y * 128;
  const int t = threadIdx.x, w = t >> 6, l = t & 63;
  const int wr = (BM == 64) ? 0 : (w >> 1);
  const int wc = (BM == 64) ? w : (w & 1);
  const int lg = l >> 4, lq = l & 15;
  const int batch = m0 / Lr, mrow = m0 % Lr;
  const int srow = l >> 2;
  const int scol = (((l & 3) ^ ((l >> 3) & 3)) << 3);   // swizzled global source col
  const unsigned short* gp[NPW];
  int lofs[NPW];
#pragma unroll
  for (int jj = 0; jj < NPW; ++jj) {
    int j = w * NPW + jj;
    if (j < NA) {
      int r = mrow + j * 16 + srow;
      gp[jj] = A + (size_t)batch * (size_t)bsA + (size_t)r * K + scol;
      lofs[jj] = j * 512;
    } else {
      int r = n0 + (j - NA) * 16 + srow;
      gp[jj] = Bt + (size_t)r * K + scol;
      lofs[jj] = BM * 32 + (j - NA) * 512;
    }
  }
  const int lsw = (lg ^ ((lq >> 1) & 3)) * 8;   // swizzled read slot
  const f32x4 fz = {0.f, 0.f, 0.f, 0.f};
  f32x4 acc[4][4];
#pragma unroll
  for (int i = 0; i < 4; ++i)
#pragma unroll
    for (int j = 0; j < 4; ++j) acc[i][j] = fz;
  const int nsteps = K >> 5;
#pragma unroll
  for (int st = 0; st < NSTAGE - 1; ++st) {
    if (st < nsteps) {
#pragma unroll
      for (int jj = 0; jj < NPW; ++jj) gload16(gp[jj] + (st << 5), &Ls[st * STRIDE + lofs[jj]]);
    }
  }
  int cur = 0;
  int nxt = (NSTAGE - 1) * STRIDE;
  for (int s = 0; s < nsteps; ++s) {
    if (s + NSTAGE - 1 < nsteps) {
      const int kk = (s + NSTAGE - 1) << 5;
#pragma unroll
      for (int jj = 0; jj < NPW; ++jj) gload16(gp[jj] + kk, &Ls[nxt + lofs[jj]]);
      asm volatile("s_waitcnt vmcnt(%0)" :: "n"((NSTAGE - 1) * NPW) : "memory");
    } else if (NSTAGE >= 3 && s + 1 < nsteps) {
      asm volatile("s_waitcnt vmcnt(%0)" :: "n"(NPW) : "memory");
    } else {
      asm volatile("s_waitcnt vmcnt(0)" ::: "memory");
    }
    __builtin_amdgcn_s_barrier();
    bf16x8 af[4], bg[4];
#pragma unroll
    for (int i = 0; i < 4; ++i) {
      af[i] = *(const bf16x8*)&Ls[cur + (wr * 64 + i * 16 + lq) * 32 + lsw];
      bg[i] = *(const bf16x8*)&Ls[cur + BM * 32 + (wc * 64 + i * 16 + lq) * 32 + lsw];
    }
#pragma unroll
    for (int i = 0; i < 4; ++i)
#pragma unroll
      for (int j = 0; j < 4; ++j)
        acc[i][j] = __builtin_amdgcn_mfma_f32_16x16x32_bf16(af[i], bg[j], acc[i][j], 0, 0, 0);
    __builtin_amdgcn_s_barrier();
    cur += STRIDE; if (cur == NSTAGE * STRIDE) cur = 0;
    nxt += STRIDE; if (nxt == NSTAGE * STRIDE) nxt = 0;
  }
  const int lr = lg << 2;
#pragma unroll
  for (int i = 0; i < 4; ++i) {
    const int rowb = m0 + wr * 64 + i * 16 + lr;
#pragma unroll
    for (int j = 0; j < 4; ++j) {
      const int col = n0 + wc * 64 + j * 16 + lq;
      const float bv = bias[col];
      float v0 = acc[i][j][0] + bv, v1 = acc[i][j][1] + bv;
      float v2 = acc[i][j][2] + bv, v3 = acc[i][j][3] + bv;
      if (outT && col >= vt_col0) {
        const int vc = col - vt_col0;
        const int hh = vc >> 6, dd = vc & 63;
        const int bb = rowb / Lr, key = rowb % Lr;
        us4 o = { f2bf(v0), f2bf(v1), f2bf(v2), f2bf(v3) };
        *(us4*)&outT[((size_t)((bb << 4) + hh) * 64 + dd) * Lv + key] = o;
      } else if (outb2 && col >= 1024) {
        const int c2 = col - 1024;
        outb2[(size_t)(rowb + 0) * 1024 + c2] = f2bf(v0);
        outb2[(size_t)(rowb + 1) * 1024 + c2] = f2bf(v1);
        outb2[(size_t)(rowb + 2) * 1024 + c2] = f2bf(v2);
        outb2[(size_t)(rowb + 3) * 1024 + c2] = f2bf(v3);
      } else if (resx) {
        const int bb = rowb / Lr, r = rowb % Lr;
        const size_t xo = ((size_t)(bb * 4096 + chunk * 1024 + r)) * 1024 + col;
        const size_t co = ((size_t)(bb * 1024 + r)) * 1024 + col;
        float r0 = v0 + resx[xo];
        float r1 = v1 + resx[xo + 1024];
        float r2 = v2 + resx[xo + 2048];
        float r3 = v3 + resx[xo + 3072];
        resout[xo] = r0; resout[xo + 1024] = r1;
        resout[xo + 2048] = r2; resout[xo + 3072] = r3;
        rescob[co] = f2bf(r0); rescob[co + 1024] = f2bf(r1);
        rescob[co + 2048] = f2bf(r2); rescob[co + 3072] = f2bf(r3);
      } else {
        outb[(size_t)(rowb + 0) * Nout + col] = f2bf(v0);
        outb[(size_t)(rowb + 1) * Nout + col] = f2bf(v1);
        outb[(size_t)(rowb + 2) * Nout + col] = f2bf(v2);
        outb[(size_t)(rowb + 3) * Nout + col] = f2bf(v3);
      }
    }
  }
}

// ================= flash attention: LDS-staged, r14-proven (two barriers, 27.6KB) ========
// MODE 1: causal over chunk keys -> f32 partials (l, acc); grid packs 4 chunks, LPT.
// MODE 3: comp attn, 4-way split-K -> f32 partials (merge in separate k_fam --
//         r18 proved in-kernel device-fence merge costs ~65us/dispatch in fences).
// MODE 2: resume chunk partials, add 256 gctx keys -> normalized O bf16.
template <int MODE>
__global__ __launch_bounds__(256) void k_fa(
    const unsigned short* __restrict__ Q, long long q_bs, int q_stride, int q_row0,
    const unsigned short* __restrict__ K, long long k_bs, int k_stride,
    const unsigned short* __restrict__ V, int Lk,
    unsigned short* __restrict__ O, int Lq_out,
    float* __restrict__ pl, float* __restrict__ pacc) {
  __shared__ unsigned short Ks[64 * 72];
  __shared__ unsigned short Vs[64 * 72];
  __shared__ unsigned short Ps[4 * 16 * 72];
  const int t = threadIdx.x, w = t >> 6, l = t & 63;
  const int lg = l >> 4, lq = l & 15;
  const int bh = blockIdx.x & 31;
  const int rest = blockIdx.x >> 5;
  const int b = bh >> 4, h = bh & 15;
  int qg, koff, ntiles;
  if (MODE == 1)      { qg = 15 - (rest & 15); koff = (rest >> 4) << 10; ntiles = qg + 1; }
  else if (MODE == 3) { qg = rest & 3;         koff = (rest >> 2) << 8;  ntiles = 4; }
  else                { qg = rest;             koff = 0;                 ntiles = 4; }
  const int qloc = qg * 64 + w * 16 + lq;
  const int qglob = q_row0 + (MODE == 1 ? koff : 0) + qloc;
  const unsigned short* qp = Q + (size_t)b * (size_t)q_bs + (size_t)qglob * q_stride + h * 64;
  bf16x8 qf0 = *(const bf16x8*)&qp[lg * 8];
  bf16x8 qf1 = *(const bf16x8*)&qp[32 + lg * 8];
  const f32x4 fz = {0.f, 0.f, 0.f, 0.f};
  const int pidx = (MODE == 2 ? 0 : (koff << 5)) + bh * (MODE == 3 ? 256 : 1024) + qloc;
  f32x4 acc0, acc1, acc2, acc3;
  float lbase = 0.f;
  if (MODE == 2) {
    lbase = pl[pidx];
    const float* pb = &pacc[(size_t)pidx * 64];
    float4 a0 = *(const float4*)&pb[0 * 16 + lg * 4];
    float4 a1 = *(const float4*)&pb[1 * 16 + lg * 4];
    float4 a2 = *(const float4*)&pb[2 * 16 + lg * 4];
    float4 a3 = *(const float4*)&pb[3 * 16 + lg * 4];
    acc0[0] = a0.x; acc0[1] = a0.y; acc0[2] = a0.z; acc0[3] = a0.w;
    acc1[0] = a1.x; acc1[1] = a1.y; acc1[2] = a1.z; acc1[3] = a1.w;
    acc2[0] = a2.x; acc2[1] = a2.y; acc2[2] = a2.z; acc2[3] = a2.w;
    acc3[0] = a3.x; acc3[1] = a3.y; acc3[2] = a3.z; acc3[3] = a3.w;
  } else {
    acc0 = fz; acc1 = fz; acc2 = fz; acc3 = fz;
  }
  float psum = 0.f;
  const int sr = t >> 2, sc = (t & 3) << 4;
  const unsigned short* kbp = K + (size_t)b * (size_t)k_bs + (size_t)koff * k_stride + h * 64;
  const unsigned short* vbp = V + (size_t)(((b << 4) + h) * 64) * Lk + koff;
  unsigned short* pw = &Ps[(w * 16 + lq) * 72];
  bf16x8 kr0, kr1, vr0, vr1;
  {
    const unsigned short* kp = kbp + (size_t)sr * k_stride + sc;
    kr0 = *(const bf16x8*)kp; kr1 = *(const bf16x8*)(kp + 8);
    const unsigned short* vp = vbp + (size_t)sr * Lk + sc;
    vr0 = *(const bf16x8*)vp; vr1 = *(const bf16x8*)(vp + 8);
  }
#define KFA_SM(Z, KH) do { \
    float e0_ = Z[0] * SCALE_L2E - M0_L2E; \
    float e1_ = Z[1] * SCALE_L2E - M0_L2E; \
    float e2_ = Z[2] * SCALE_L2E - M0_L2E; \
    float e3_ = Z[3] * SCALE_L2E - M0_L2E; \
    if (MODE == 1) { \
      int kg_ = k0 + (KH) * 16 + lg * 4; \
      if (kg_ + 0 > qloc) e0_ = -1e9f; \
      if (kg_ + 1 > qloc) e1_ = -1e9f; \
      if (kg_ + 2 > qloc) e2_ = -1e9f; \
      if (kg_ + 3 > qloc) e3_ = -1e9f; \
    } \
    float p0_ = exp2f(e0_), p1_ = exp2f(e1_), p2_ = exp2f(e2_), p3_ = exp2f(e3_); \
    psum += (p0_ + p1_) + (p2_ + p3_); \
    *(unsigned*)&pw[(KH) * 16 + lg * 4]     = pack2bf(p0_, p1_); \
    *(unsigned*)&pw[(KH) * 16 + lg * 4 + 2] = pack2bf(p2_, p3_); \
  } while (0)
#define KFA_MFMA(A_, B_, C_) __builtin_amdgcn_mfma_f32_16x16x32_bf16(A_, B_, C_, 0, 0, 0)
  for (int kt = 0; kt < ntiles; ++kt) {
    const int k0 = kt * 64;
    __syncthreads();
    *(bf16x8*)&Ks[sr * 72 + sc] = kr0; *(bf16x8*)&Ks[sr * 72 + sc + 8] = kr1;
    *(bf16x8*)&Vs[sr * 72 + sc] = vr0; *(bf16x8*)&Vs[sr * 72 + sc + 8] = vr1;
    __syncthreads();
    if (kt + 1 < ntiles) {
      const unsigned short* kp = kbp + (size_t)(k0 + 64 + sr) * k_stride + sc;
      kr0 = *(const bf16x8*)kp; kr1 = *(const bf16x8*)(kp + 8);
      const unsigned short* vp = vbp + (size_t)sr * Lk + k0 + 64 + sc;
      vr0 = *(const bf16x8*)vp; vr1 = *(const bf16x8*)(vp + 8);
    }
    f32x4 z0 = fz, z1 = fz, z2 = fz, z3 = fz;
    __builtin_amdgcn_s_setprio(1);
    z0 = KFA_MFMA(*(const bf16x8*)&Ks[(0 * 16 + lq) * 72 + lg * 8], qf0, z0);
    z1 = KFA_MFMA(*(const bf16x8*)&Ks[(1 * 16 + lq) * 72 + lg * 8], qf0, z1);
    z2 = KFA_MFMA(*(const bf16x8*)&Ks[(2 * 16 + lq) * 72 + lg * 8], qf0, z2);
    z3 = KFA_MFMA(*(const bf16x8*)&Ks[(3 * 16 + lq) * 72 + lg * 8], qf0, z3);
    z0 = KFA_MFMA(*(const bf16x8*)&Ks[(0 * 16 + lq) * 72 + 32 + lg * 8], qf1, z0);
    z1 = KFA_MFMA(*(const bf16x8*)&Ks[(1 * 16 + lq) * 72 + 32 + lg * 8], qf1, z1);
    z2 = KFA_MFMA(*(const bf16x8*)&Ks[(2 * 16 + lq) * 72 + 32 + lg * 8], qf1, z2);
    z3 = KFA_MFMA(*(const bf16x8*)&Ks[(3 * 16 + lq) * 72 + 32 + lg * 8], qf1, z3);
    __builtin_amdgcn_s_setprio(0);
    KFA_SM(z0, 0); KFA_SM(z1, 1); KFA_SM(z2, 2); KFA_SM(z3, 3);
    asm volatile("s_waitcnt lgkmcnt(0)" ::: "memory");
    __builtin_amdgcn_sched_barrier(0);
    bf16x8 pf0 = *(const bf16x8*)&pw[lg * 8];
    bf16x8 pf1 = *(const bf16x8*)&pw[32 + lg * 8];
    asm volatile("" ::: "memory");
    __builtin_amdgcn_sched_barrier(0);
    __builtin_amdgcn_s_setprio(1);
    acc0 = KFA_MFMA(*(const bf16x8*)&Vs[(0 * 16 + lq) * 72 + lg * 8], pf0, acc0);
    acc1 = KFA_MFMA(*(const bf16x8*)&Vs[(1 * 16 + lq) * 72 + lg * 8], pf0, acc1);
    acc2 = KFA_MFMA(*(const bf16x8*)&Vs[(2 * 16 + lq) * 72 + lg * 8], pf0, acc2);
    acc3 = KFA_MFMA(*(const bf16x8*)&Vs[(3 * 16 + lq) * 72 + lg * 8], pf0, acc3);
    acc0 = KFA_MFMA(*(const bf16x8*)&Vs[(0 * 16 + lq) * 72 + 32 + lg * 8], pf1, acc0);
    acc1 = KFA_MFMA(*(const bf16x8*)&Vs[(1 * 16 + lq) * 72 + 32 + lg * 8], pf1, acc1);
    acc2 = KFA_MFMA(*(const bf16x8*)&Vs[(2 * 16 + lq) * 72 + 32 + lg * 8], pf1, acc2);
    acc3 = KFA_MFMA(*(const bf16x8*)&Vs[(3 * 16 + lq) * 72 + 32 + lg * 8], pf1, acc3);
    __builtin_amdgcn_s_setprio(0);
  }
#undef KFA_SM
#undef KFA_MFMA
  psum += __shfl_xor(psum, 16);
  psum += __shfl_xor(psum, 32);
  if (MODE == 2) {
    float inv = 1.f / (lbase + psum);
    size_t ob = ((size_t)b * Lq_out + qloc) * 1024 + h * 64;
    us4 o0 = { f2bf(acc0[0] * inv), f2bf(acc0[1] * inv), f2bf(acc0[2] * inv), f2bf(acc0[3] * inv) };
    us4 o1 = { f2bf(acc1[0] * inv), f2bf(acc1[1] * inv), f2bf(acc1[2] * inv), f2bf(acc1[3] * inv) };
    us4 o2 = { f2bf(acc2[0] * inv), f2bf(acc2[1] * inv), f2bf(acc2[2] * inv), f2bf(acc2[3] * inv) };
    us4 o3 = { f2bf(acc3[0] * inv), f2bf(acc3[1] * inv), f2bf(acc3[2] * inv), f2bf(acc3[3] * inv) };
    *(us4*)&O[ob + 0 * 16 + lg * 4] = o0;
    *(us4*)&O[ob + 1 * 16 + lg * 4] = o1;
    *(us4*)&O[ob + 2 * 16 + lg * 4] = o2;
    *(us4*)&O[ob + 3 * 16 + lg * 4] = o3;
  } else {
    if (lg == 0) pl[pidx] = psum;
    float* pb = &pacc[(size_t)pidx * 64];
    *(float4*)&pb[0 * 16 + lg * 4] = make_float4(acc0[0], acc0[1], acc0[2], acc0[3]);
    *(float4*)&pb[1 * 16 + lg * 4] = make_float4(acc1[0], acc1[1], acc1[2], acc1[3]);
    *(float4*)&pb[2 * 16 + lg * 4] = make_float4(acc2[0], acc2[1], acc2[2], acc2[3]);
    *(float4*)&pb[3 * 16 + lg * 4] = make_float4(acc3[0], acc3[1], acc3[2], acc3[3]);
  }
}

// ---------- merge 4 split-K partials -> attc bf16 (B,256,1024) ----------
__global__ __launch_bounds__(256) void k_fam(const float* __restrict__ pl0,
                                             const float* __restrict__ pacc0,
                                             unsigned short* __restrict__ attc) {
  int i = blockIdx.x * 256 + threadIdx.x;   // 131072 threads
  int row = i >> 4, d4 = (i & 15) << 2;
  float lsum = 0.f;
  float4 o = make_float4(0.f, 0.f, 0.f, 0.f);
#pragma unroll
  for (int s = 0; s < 4; ++s) {
    lsum += pl0[s * 8192 + row];
    float4 a = *(const float4*)&pacc0[((size_t)(s * 8192 + row)) * 64 + d4];
    o.x += a.x; o.y += a.y; o.z += a.z; o.w += a.w;
  }
  float inv = 1.f / lsum;
  int b = row >> 12, h = (row >> 8) & 15, q = row & 255;
  us4 ov = { f2bf(o.x * inv), f2bf(o.y * inv), f2bf(o.z * inv), f2bf(o.w * inv) };
  *(us4*)&attc[((size_t)(b * 256 + q)) * 1024 + h * 64 + d4] = ov;
}

extern "C" void kernel_launch(void* const* d_in, const int* in_sizes, int n_in,
                              void* d_out, int out_size, void* d_ws, size_t ws_size,
                              hipStream_t stream) {
  const float* x     = (const float*)d_in[0];
  const float* sq    = (const float*)d_in[1];
  const float* cq_w  = (const float*)d_in[2];
  const float* cq_b  = (const float*)d_in[3];
  const float* ck_w  = (const float*)d_in[4];
  const float* ck_b  = (const float*)d_in[5];
  const float* cv_w  = (const float*)d_in[6];
  const float* cv_b  = (const float*)d_in[7];
  const float* co_w  = (const float*)d_in[8];
  const float* co_b  = (const float*)d_in[9];
  const float* qkv_w = (const float*)d_in[10];
  const float* qkv_b = (const float*)d_in[11];
  const float* lo_w  = (const float*)d_in[12];
  const float* lo_b  = (const float*)d_in[13];
  float* out = (float*)d_out;

  char* ws = (char*)d_ws;
  size_t off = 0;
  auto alloc = [&](size_t bytes) -> void* {
    void* p = ws + off;
    off += (bytes + 255) & ~(size_t)255;
    return p;
  };
  unsigned short* xb    = (unsigned short*)alloc(16777216);  // x bf16 (B,4096,1024)
  unsigned short* sqb   = (unsigned short*)alloc(524288);
  unsigned short* cow16 = (unsigned short*)alloc(2097152);   // co_w bf16 row-major
  unsigned short* wqt   = (unsigned short*)alloc(2097152);
  unsigned short* wkvt  = (unsigned short*)alloc(4194304);   // [ck^T ; cv^T]
  unsigned short* wlot  = (unsigned short*)alloc(2097152);
  unsigned short* wqkvt = (unsigned short*)alloc(6291456);   // qkv^T (3072,1024)
  unsigned short* w2t   = (unsigned short*)alloc(4194304);   // (co_w @ qkv_w[:,1024:])^T
  float*          bias2 = (float*)alloc(8192);
  float*          kvb   = (float*)alloc(8192);
  float*          zbias = (float*)alloc(4096);
  float*          part  = (float*)alloc(131072);
  unsigned short* qs    = (unsigned short*)alloc(524288);    // summary q (256,1024)
  unsigned short* qx    = (unsigned short*)alloc(16777216);  // Q of x (B,4096,1024)
  unsigned short* kx    = (unsigned short*)alloc(16777216);  // K of x (B,4096,1024)
  unsigned short* vtx   = (unsigned short*)alloc(16777216);  // V^T of x (B,16,64,4096)
  unsigned short* gk    = (unsigned short*)alloc(1048576);   // gctx K (B,256,1024)
  unsigned short* gvt   = (unsigned short*)alloc(1048576);   // gctx V^T (B,16,64,256)
  unsigned short* kc    = (unsigned short*)alloc(4194304);   // comp K (B,1024,1024)
  unsigned short* vtc   = (unsigned short*)alloc(4194304);   // comp V^T (B,16,64,1024)
  unsigned short* attc  = (unsigned short*)alloc(1048576);   // comp attn out (B,256,1024)
  unsigned short* attl  = (unsigned short*)alloc(4194304);   // local attn out (B,1024,1024)
  unsigned short* cob   = (unsigned short*)alloc(4194304);   // chunk_out bf16
  float*          plb   = (float*)alloc(524288);             // (4,B,16,1024) l partials
  float*          pacc  = (float*)alloc(33554432);           // (4,B,16,1024,64) acc partials
  float*          pl0   = (float*)alloc(131072);             // (4,B,16,256) comp split-K l
  float*          pacc0 = (float*)alloc(8388608);            // (4,B,16,256,64) comp split-K acc

  // ---- prep (one fused dispatch) ----
  k_prep<<<16768, 256, 0, stream>>>(x, sq, co_w, xb, sqb, cow16,
                                    cq_w, ck_w, cv_w, lo_w, qkv_w,
                                    wqt, wkvt, wlot, wqkvt,
                                    qkv_w, co_b, part);
  k_bias2b<<<9, 256, 0, stream>>>(part, qkv_b, ck_b, cv_b, bias2, kvb, zbias);
  // q_summary
  k_gemm<64><<<dim3(4, 8), 128, 0, stream>>>(sqb, 0, 256, wqt, cq_b, qs, 1024, nullptr,
                                             nullptr, 0, 0, nullptr, nullptr, nullptr, 0, 1024, 1024);
  // W2^T
  k_gemm<128><<<dim3(16, 8), 256, 0, stream>>>(wqkvt + 1024 * 1024, 0, 2048, cow16, zbias,
                                               w2t, 1024, nullptr, nullptr, 0, 0,
                                               nullptr, nullptr, nullptr, 0, 1024, 1024);
  // big qkv projection: Q->qx, K->kx, V->vtx (BM=256: 768 blocks, 3/CU resident)
  k_gemm<256><<<dim3(32, 24), 512, 0, stream>>>(xb, 4096LL * 1024, 4096, wqkvt, qkv_b,
                                                qx, 1024, kx, vtx, 4096, 2048,
                                                nullptr, nullptr, nullptr, 0, 3072, 1024);
  // causal partials for ALL chunks (LPT-ordered grid)
  k_fa<1><<<2048, 256, 0, stream>>>(qx, 4096LL * 1024, 1024, 0,
                                    kx, 4096LL * 1024, 1024,
                                    vtx, 4096, nullptr, 0, plb, pacc);

  auto comp = [&](const unsigned short* inA, long long bsA) {
    k_gemm<64><<<dim3(32, 16), 128, 0, stream>>>(inA, bsA, 1024, wkvt, kvb,
                                                 kc, 1024, nullptr, vtc, 1024, 1024,
                                                 nullptr, nullptr, nullptr, 0, 2048, 1024);
    k_fa<3><<<512, 256, 0, stream>>>(qs, 0LL, 1024, 0,
                                     kc, 1024LL * 1024, 1024,
                                     vtc, 1024, nullptr, 0, pl0, pacc0);
    k_fam<<<512, 256, 0, stream>>>(pl0, pacc0, attc);
    k_gemm<64><<<dim3(8, 16), 128, 0, stream>>>(attc, 256LL * 1024, 256, w2t, bias2,
                                                gk, 1024, nullptr, gvt, 256, 1024,
                                                nullptr, nullptr, nullptr, 0, 2048, 1024);
  };

  comp(xb, 4096LL * 1024);  // gctx_0 from raw chunk 0
  for (int i = 0; i < 4; ++i) {
    k_fa<2><<<512, 256, 0, stream>>>(qx, 4096LL * 1024, 1024, i * 1024,
                                     gk, 256LL * 1024, 1024,
                                     gvt, 256, attl, 1024,
                                     plb + (size_t)i * 32768, pacc + (size_t)i * 32768 * 64);
    k_gemm<64><<<dim3(32, 8), 128, 0, stream>>>(attl, 1024LL * 1024, 1024, wlot, lo_b,
                                                nullptr, 1024, nullptr, nullptr, 0, 0,
                                                x, out, cob, i, 1024, 1024);
    if (i < 3) comp(cob, 1024LL * 1024);
  }
}

// Round 20
// 468.011 us; speedup vs baseline: 1.5465x; 1.0040x over previous
//
#include <hip/hip_runtime.h>

using bf16x8 = __attribute__((ext_vector_type(8))) short;
using f32x4  = __attribute__((ext_vector_type(4))) float;
using us4    = __attribute__((ext_vector_type(4))) unsigned short;

static __device__ __forceinline__ unsigned short f2bf(float x) {
  union { float f; unsigned u; } v; v.f = x;
  unsigned r = v.u + 0x7FFFu + ((v.u >> 16) & 1u);
  return (unsigned short)(r >> 16);
}
static __device__ __forceinline__ unsigned pack2bf(float a, float b) {
  return (unsigned)f2bf(a) | ((unsigned)f2bf(b) << 16);
}
static __device__ __forceinline__ void gload16(const unsigned short* g, unsigned short* lds_base) {
  __builtin_amdgcn_global_load_lds(
      (const __attribute__((address_space(1))) unsigned int*)g,
      (__attribute__((address_space(3))) unsigned int*)lds_base, 16, 0, 0);
}

// static softmax max: p = exp(s*0.125 - 10) computed as exp2(s*0.125*log2e - 10*log2e)
#define SCALE_L2E 0.18033688011112042f
#define M0_L2E    14.426950408889634f

// ---------- fused prep: cvt3 (9472 blk) + weight transposes (7168 blk) + bias2a (128 blk) ----------
__global__ __launch_bounds__(256) void k_prep(
    const float* __restrict__ x, const float* __restrict__ sq, const float* __restrict__ cw,
    unsigned short* __restrict__ xb, unsigned short* __restrict__ sqb,
    unsigned short* __restrict__ cwb,
    const float* __restrict__ cq, const float* __restrict__ ck, const float* __restrict__ cv,
    const float* __restrict__ lo, const float* __restrict__ qkv,
    unsigned short* __restrict__ wqt, unsigned short* __restrict__ wkvt,
    unsigned short* __restrict__ wlot, unsigned short* __restrict__ wqkvt,
    const float* __restrict__ qkv_w, const float* __restrict__ co_b,
    float* __restrict__ part) {
  __shared__ float tile[32][33];
  int id = blockIdx.x;
  const int t = threadIdx.x;
  if (id < 9472) {  // ---- f32 -> bf16 converts ----
    const float* in; unsigned short* out; int i;
    if (id < 8192)      { in = x;  out = xb;  i = id * 256 + t; }
    else if (id < 8448) { in = sq; out = sqb; i = (id - 8192) * 256 + t; }
    else                { in = cw; out = cwb; i = (id - 8448) * 256 + t; }
    float4 v = ((const float4*)in)[i];
    us4 o = { f2bf(v.x), f2bf(v.y), f2bf(v.z), f2bf(v.w) };
    ((us4*)out)[i] = o;
  } else if (id < 16640) {  // ---- weight transposes: W (1024,N) f32 -> Wt (N,1024) bf16 ----
    id -= 9472;
    const float* W; unsigned short* Wt; int N;
    if (id < 1024)      { W = cq;  Wt = wqt;                N = 1024; }
    else if (id < 2048) { W = ck;  Wt = wkvt;               N = 1024; id -= 1024; }
    else if (id < 3072) { W = cv;  Wt = wkvt + 1024 * 1024; N = 1024; id -= 2048; }
    else if (id < 4096) { W = lo;  Wt = wlot;               N = 1024; id -= 3072; }
    else                { W = qkv; Wt = wqkvt;              N = 3072; id -= 4096; }
    int ntb = N >> 5;
    int nb = (id % ntb) * 32, kb = (id / ntb) * 32;
    int k = t >> 3, n4 = (t & 7) << 2;
    float4 v = *(const float4*)&W[(size_t)(kb + k) * N + nb + n4];
    tile[k][n4] = v.x; tile[k][n4 + 1] = v.y; tile[k][n4 + 2] = v.z; tile[k][n4 + 3] = v.w;
    __syncthreads();
    int n = t >> 3, k4 = (t & 7) << 2;
    us4 o = { f2bf(tile[k4][n]), f2bf(tile[k4 + 1][n]), f2bf(tile[k4 + 2][n]), f2bf(tile[k4 + 3][n]) };
    *(us4*)&Wt[(size_t)(nb + n) * 1024 + kb + k4] = o;
  } else {  // ---- bias2 stage A: partial sums over 64-j slices ----
    id -= 16640;
    int nb = id & 7, jb = id >> 3;
    int n = nb * 256 + t;
    float s = 0.f;
    int j0 = jb * 64;
#pragma unroll 4
    for (int j = j0; j < j0 + 64; ++j) s += co_b[j] * qkv_w[(size_t)j * 3072 + 1024 + n];
    part[jb * 2048 + n] = s;
  }
}

// ---------- bias2 stage B + kvb/zbias fill ----------
__global__ __launch_bounds__(256) void k_bias2b(const float* __restrict__ part,
                                                const float* __restrict__ qkv_b,
                                                const float* __restrict__ ck_b,
                                                const float* __restrict__ cv_b,
                                                float* __restrict__ bias2,
                                                float* __restrict__ kvb,
                                                float* __restrict__ zbias) {
  int id = blockIdx.x, t = threadIdx.x;
  if (id < 8) {
    int n = id * 256 + t;
    float s = qkv_b[1024 + n];
#pragma unroll
    for (int jb = 0; jb < 16; ++jb) s += part[jb * 2048 + n];
    bias2[n] = s;
  } else {
    for (int j = t; j < 1024; j += 256) {
      kvb[j] = ck_b[j]; kvb[1024 + j] = cv_b[j]; zbias[j] = 0.f;
    }
  }
}

// ---------- GEMM: C = A(M,K)bf16 @ Bt(N,K)^T + bias ----------
// NSTAGE LDS pipeline (r12) + T2 XOR swizzle (r13: conflicts 6.29M->0) + BM=256
// (r14: big qkv 75.6->62.9us). NO XCD block swizzle (r16: default order already optimal).
template <int BM, int NSTAGE = (BM == 256 ? 2 : 3)>
__global__ __launch_bounds__(BM * 2) void k_gemm(
    const unsigned short* __restrict__ A, long long bsA, int Lr,
    const unsigned short* __restrict__ Bt, const float* __restrict__ bias,
    unsigned short* __restrict__ outb, int Nout,
    unsigned short* __restrict__ outb2,
    unsigned short* __restrict__ outT, int Lv, int vt_col0,
    const float* __restrict__ resx, float* __restrict__ resout,
    unsigned short* __restrict__ rescob, int chunk,
    int N, int K) {
  constexpr int NWAVES = (BM * 2) / 64;
  constexpr int NA = BM / 16;
  constexpr int NINST = NA + 8;
  constexpr int NPW = NINST / NWAVES;
  static_assert(NPW * NWAVES == NINST, "staging split");
  constexpr int STRIDE = (BM + 128) * 32;
  __shared__ unsigned short Ls[NSTAGE * STRIDE];
  const int m0 = blockIdx.x * BM, n0 = blockIdx.y * 128;
  const int t = threadIdx.x, w = t >> 6, l = t & 63;
  const int wr = (BM == 64) ? 0 : (w >> 1);
  const int wc = (BM == 64) ? w : (w & 1);
  const int lg = l >> 4, lq = l & 15;
  const int batch = m0 / Lr, mrow = m0 % Lr;
  const int srow = l >> 2;
  const int scol = (((l & 3) ^ ((l >> 3) & 3)) << 3);   // swizzled global source col
  const unsigned short* gp[NPW];
  int lofs[NPW];
#pragma unroll
  for (int jj = 0; jj < NPW; ++jj) {
    int j = w * NPW + jj;
    if (j < NA) {
      int r = mrow + j * 16 + srow;
      gp[jj] = A + (size_t)batch * (size_t)bsA + (size_t)r * K + scol;
      lofs[jj] = j * 512;
    } else {
      int r = n0 + (j - NA) * 16 + srow;
      gp[jj] = Bt + (size_t)r * K + scol;
      lofs[jj] = BM * 32 + (j - NA) * 512;
    }
  }
  const int lsw = (lg ^ ((lq >> 1) & 3)) * 8;   // swizzled read slot
  const f32x4 fz = {0.f, 0.f, 0.f, 0.f};
  f32x4 acc[4][4];
#pragma unroll
  for (int i = 0; i < 4; ++i)
#pragma unroll
    for (int j = 0; j < 4; ++j) acc[i][j] = fz;
  const int nsteps = K >> 5;
#pragma unroll
  for (int st = 0; st < NSTAGE - 1; ++st) {
    if (st < nsteps) {
#pragma unroll
      for (int jj = 0; jj < NPW; ++jj) gload16(gp[jj] + (st << 5), &Ls[st * STRIDE + lofs[jj]]);
    }
  }
  int cur = 0;
  int nxt = (NSTAGE - 1) * STRIDE;
  for (int s = 0; s < nsteps; ++s) {
    if (s + NSTAGE - 1 < nsteps) {
      const int kk = (s + NSTAGE - 1) << 5;
#pragma unroll
      for (int jj = 0; jj < NPW; ++jj) gload16(gp[jj] + kk, &Ls[nxt + lofs[jj]]);
      asm volatile("s_waitcnt vmcnt(%0)" :: "n"((NSTAGE - 1) * NPW) : "memory");
    } else if (NSTAGE >= 3 && s + 1 < nsteps) {
      asm volatile("s_waitcnt vmcnt(%0)" :: "n"(NPW) : "memory");
    } else {
      asm volatile("s_waitcnt vmcnt(0)" ::: "memory");
    }
    __builtin_amdgcn_s_barrier();
    bf16x8 af[4], bg[4];
#pragma unroll
    for (int i = 0; i < 4; ++i) {
      af[i] = *(const bf16x8*)&Ls[cur + (wr * 64 + i * 16 + lq) * 32 + lsw];
      bg[i] = *(const bf16x8*)&Ls[cur + BM * 32 + (wc * 64 + i * 16 + lq) * 32 + lsw];
    }
#pragma unroll
    for (int i = 0; i < 4; ++i)
#pragma unroll
      for (int j = 0; j < 4; ++j)
        acc[i][j] = __builtin_amdgcn_mfma_f32_16x16x32_bf16(af[i], bg[j], acc[i][j], 0, 0, 0);
    __builtin_amdgcn_s_barrier();
    cur += STRIDE; if (cur == NSTAGE * STRIDE) cur = 0;
    nxt += STRIDE; if (nxt == NSTAGE * STRIDE) nxt = 0;
  }
  const int lr = lg << 2;
#pragma unroll
  for (int i = 0; i < 4; ++i) {
    const int rowb = m0 + wr * 64 + i * 16 + lr;
#pragma unroll
    for (int j = 0; j < 4; ++j) {
      const int col = n0 + wc * 64 + j * 16 + lq;
      const float bv = bias[col];
      float v0 = acc[i][j][0] + bv, v1 = acc[i][j][1] + bv;
      float v2 = acc[i][j][2] + bv, v3 = acc[i][j][3] + bv;
      if (outT && col >= vt_col0) {
        const int vc = col - vt_col0;
        const int hh = vc >> 6, dd = vc & 63;
        const int bb = rowb / Lr, key = rowb % Lr;
        us4 o = { f2bf(v0), f2bf(v1), f2bf(v2), f2bf(v3) };
        *(us4*)&outT[((size_t)((bb << 4) + hh) * 64 + dd) * Lv + key] = o;
      } else if (outb2 && col >= 1024) {
        const int c2 = col - 1024;
        outb2[(size_t)(rowb + 0) * 1024 + c2] = f2bf(v0);
        outb2[(size_t)(rowb + 1) * 1024 + c2] = f2bf(v1);
        outb2[(size_t)(rowb + 2) * 1024 + c2] = f2bf(v2);
        outb2[(size_t)(rowb + 3) * 1024 + c2] = f2bf(v3);
      } else if (resx) {
        const int bb = rowb / Lr, r = rowb % Lr;
        const size_t xo = ((size_t)(bb * 4096 + chunk * 1024 + r)) * 1024 + col;
        const size_t co = ((size_t)(bb * 1024 + r)) * 1024 + col;
        float r0 = v0 + resx[xo];
        float r1 = v1 + resx[xo + 1024];
        float r2 = v2 + resx[xo + 2048];
        float r3 = v3 + resx[xo + 3072];
        resout[xo] = r0; resout[xo + 1024] = r1;
        resout[xo + 2048] = r2; resout[xo + 3072] = r3;
        rescob[co] = f2bf(r0); rescob[co + 1024] = f2bf(r1);
        rescob[co + 2048] = f2bf(r2); rescob[co + 3072] = f2bf(r3);
      } else {
        outb[(size_t)(rowb + 0) * Nout + col] = f2bf(v0);
        outb[(size_t)(rowb + 1) * Nout + col] = f2bf(v1);
        outb[(size_t)(rowb + 2) * Nout + col] = f2bf(v2);
        outb[(size_t)(rowb + 3) * Nout + col] = f2bf(v3);
      }
    }
  }
}

// ================= flash attention: LDS-staged, r14-proven (two barriers, 27.6KB) ========
// MODE 1: causal over chunk keys -> f32 partials (l, acc); grid packs 4 chunks, LPT.
// MODE 3: comp attn, 4-way split-K -> f32 partials (merge in separate k_fam --
//         r18 proved in-kernel device-fence merge costs ~65us/dispatch in fences).
// MODE 2: resume chunk partials, add 256 gctx keys -> normalized O bf16.
template <int MODE>
__global__ __launch_bounds__(256) void k_fa(
    const unsigned short* __restrict__ Q, long long q_bs, int q_stride, int q_row0,
    const unsigned short* __restrict__ K, long long k_bs, int k_stride,
    const unsigned short* __restrict__ V, int Lk,
    unsigned short* __restrict__ O, int Lq_out,
    float* __restrict__ pl, float* __restrict__ pacc) {
  __shared__ unsigned short Ks[64 * 72];
  __shared__ unsigned short Vs[64 * 72];
  __shared__ unsigned short Ps[4 * 16 * 72];
  const int t = threadIdx.x, w = t >> 6, l = t & 63;
  const int lg = l >> 4, lq = l & 15;
  const int bh = blockIdx.x & 31;
  const int rest = blockIdx.x >> 5;
  const int b = bh >> 4, h = bh & 15;
  int qg, koff, ntiles;
  if (MODE == 1)      { qg = 15 - (rest & 15); koff = (rest >> 4) << 10; ntiles = qg + 1; }
  else if (MODE == 3) { qg = rest & 3;         koff = (rest >> 2) << 8;  ntiles = 4; }
  else                { qg = rest;             koff = 0;                 ntiles = 4; }
  const int qloc = qg * 64 + w * 16 + lq;
  const int qglob = q_row0 + (MODE == 1 ? koff : 0) + qloc;
  const unsigned short* qp = Q + (size_t)b * (size_t)q_bs + (size_t)qglob * q_stride + h * 64;
  bf16x8 qf0 = *(const bf16x8*)&qp[lg * 8];
  bf16x8 qf1 = *(const bf16x8*)&qp[32 + lg * 8];
  const f32x4 fz = {0.f, 0.f, 0.f, 0.f};
  const int pidx = (MODE == 2 ? 0 : (koff << 5)) + bh * (MODE == 3 ? 256 : 1024) + qloc;
  f32x4 acc0, acc1, acc2, acc3;
  float lbase = 0.f;
  if (MODE == 2) {
    lbase = pl[pidx];
    const float* pb = &pacc[(size_t)pidx * 64];
    float4 a0 = *(const float4*)&pb[0 * 16 + lg * 4];
    float4 a1 = *(const float4*)&pb[1 * 16 + lg * 4];
    float4 a2 = *(const float4*)&pb[2 * 16 + lg * 4];
    float4 a3 = *(const float4*)&pb[3 * 16 + lg * 4];
    acc0[0] = a0.x; acc0[1] = a0.y; acc0[2] = a0.z; acc0[3] = a0.w;
    acc1[0] = a1.x; acc1[1] = a1.y; acc1[2] = a1.z; acc1[3] = a1.w;
    acc2[0] = a2.x; acc2[1] = a2.y; acc2[2] = a2.z; acc2[3] = a2.w;
    acc3[0] = a3.x; acc3[1] = a3.y; acc3[2] = a3.z; acc3[3] = a3.w;
  } else {
    acc0 = fz; acc1 = fz; acc2 = fz; acc3 = fz;
  }
  float psum = 0.f;
  const int sr = t >> 2, sc = (t & 3) << 4;
  const unsigned short* kbp = K + (size_t)b * (size_t)k_bs + (size_t)koff * k_stride + h * 64;
  const unsigned short* vbp = V + (size_t)(((b << 4) + h) * 64) * Lk + koff;
  unsigned short* pw = &Ps[(w * 16 + lq) * 72];
  bf16x8 kr0, kr1, vr0, vr1;
  {
    const unsigned short* kp = kbp + (size_t)sr * k_stride + sc;
    kr0 = *(const bf16x8*)kp; kr1 = *(const bf16x8*)(kp + 8);
    const unsigned short* vp = vbp + (size_t)sr * Lk + sc;
    vr0 = *(const bf16x8*)vp; vr1 = *(const bf16x8*)(vp + 8);
  }
#define KFA_SM(Z, KH) do { \
    float e0_ = Z[0] * SCALE_L2E - M0_L2E; \
    float e1_ = Z[1] * SCALE_L2E - M0_L2E; \
    float e2_ = Z[2] * SCALE_L2E - M0_L2E; \
    float e3_ = Z[3] * SCALE_L2E - M0_L2E; \
    if (MODE == 1) { \
      int kg_ = k0 + (KH) * 16 + lg * 4; \
      if (kg_ + 0 > qloc) e0_ = -1e9f; \
      if (kg_ + 1 > qloc) e1_ = -1e9f; \
      if (kg_ + 2 > qloc) e2_ = -1e9f; \
      if (kg_ + 3 > qloc) e3_ = -1e9f; \
    } \
    float p0_ = exp2f(e0_), p1_ = exp2f(e1_), p2_ = exp2f(e2_), p3_ = exp2f(e3_); \
    psum += (p0_ + p1_) + (p2_ + p3_); \
    *(unsigned*)&pw[(KH) * 16 + lg * 4]     = pack2bf(p0_, p1_); \
    *(unsigned*)&pw[(KH) * 16 + lg * 4 + 2] = pack2bf(p2_, p3_); \
  } while (0)
#define KFA_MFMA(A_, B_, C_) __builtin_amdgcn_mfma_f32_16x16x32_bf16(A_, B_, C_, 0, 0, 0)
  for (int kt = 0; kt < ntiles; ++kt) {
    const int k0 = kt * 64;
    __syncthreads();
    *(bf16x8*)&Ks[sr * 72 + sc] = kr0; *(bf16x8*)&Ks[sr * 72 + sc + 8] = kr1;
    *(bf16x8*)&Vs[sr * 72 + sc] = vr0; *(bf16x8*)&Vs[sr * 72 + sc + 8] = vr1;
    __syncthreads();
    if (kt + 1 < ntiles) {
      const unsigned short* kp = kbp + (size_t)(k0 + 64 + sr) * k_stride + sc;
      kr0 = *(const bf16x8*)kp; kr1 = *(const bf16x8*)(kp + 8);
      const unsigned short* vp = vbp + (size_t)sr * Lk + k0 + 64 + sc;
      vr0 = *(const bf16x8*)vp; vr1 = *(const bf16x8*)(vp + 8);
    }
    f32x4 z0 = fz, z1 = fz, z2 = fz, z3 = fz;
    __builtin_amdgcn_s_setprio(1);
    z0 = KFA_MFMA(*(const bf16x8*)&Ks[(0 * 16 + lq) * 72 + lg * 8], qf0, z0);
    z1 = KFA_MFMA(*(const bf16x8*)&Ks[(1 * 16 + lq) * 72 + lg * 8], qf0, z1);
    z2 = KFA_MFMA(*(const bf16x8*)&Ks[(2 * 16 + lq) * 72 + lg * 8], qf0, z2);
    z3 = KFA_MFMA(*(const bf16x8*)&Ks[(3 * 16 + lq) * 72 + lg * 8], qf0, z3);
    z0 = KFA_MFMA(*(const bf16x8*)&Ks[(0 * 16 + lq) * 72 + 32 + lg * 8], qf1, z0);
    z1 = KFA_MFMA(*(const bf16x8*)&Ks[(1 * 16 + lq) * 72 + 32 + lg * 8], qf1, z1);
    z2 = KFA_MFMA(*(const bf16x8*)&Ks[(2 * 16 + lq) * 72 + 32 + lg * 8], qf1, z2);
    z3 = KFA_MFMA(*(const bf16x8*)&Ks[(3 * 16 + lq) * 72 + 32 + lg * 8], qf1, z3);
    __builtin_amdgcn_s_setprio(0);
    KFA_SM(z0, 0); KFA_SM(z1, 1); KFA_SM(z2, 2); KFA_SM(z3, 3);
    asm volatile("s_waitcnt lgkmcnt(0)" ::: "memory");
    __builtin_amdgcn_sched_barrier(0);
    bf16x8 pf0 = *(const bf16x8*)&pw[lg * 8];
    bf16x8 pf1 = *(const bf16x8*)&pw[32 + lg * 8];
    asm volatile("" ::: "memory");
    __builtin_amdgcn_sched_barrier(0);
    __builtin_amdgcn_s_setprio(1);
    acc0 = KFA_MFMA(*(const bf16x8*)&Vs[(0 * 16 + lq) * 72 + lg * 8], pf0, acc0);
    acc1 = KFA_MFMA(*(const bf16x8*)&Vs[(1 * 16 + lq) * 72 + lg * 8], pf0, acc1);
    acc2 = KFA_MFMA(*(const bf16x8*)&Vs[(2 * 16 + lq) * 72 + lg * 8], pf0, acc2);
    acc3 = KFA_MFMA(*(const bf16x8*)&Vs[(3 * 16 + lq) * 72 + lg * 8], pf0, acc3);
    acc0 = KFA_MFMA(*(const bf16x8*)&Vs[(0 * 16 + lq) * 72 + 32 + lg * 8], pf1, acc0);
    acc1 = KFA_MFMA(*(const bf16x8*)&Vs[(1 * 16 + lq) * 72 + 32 + lg * 8], pf1, acc1);
    acc2 = KFA_MFMA(*(const bf16x8*)&Vs[(2 * 16 + lq) * 72 + 32 + lg * 8], pf1, acc2);
    acc3 = KFA_MFMA(*(const bf16x8*)&Vs[(3 * 16 + lq) * 72 + 32 + lg * 8], pf1, acc3);
    __builtin_amdgcn_s_setprio(0);
  }
#undef KFA_SM
#undef KFA_MFMA
  psum += __shfl_xor(psum, 16);
  psum += __shfl_xor(psum, 32);
  if (MODE == 2) {
    float inv = 1.f / (lbase + psum);
    size_t ob = ((size_t)b * Lq_out + qloc) * 1024 + h * 64;
    us4 o0 = { f2bf(acc0[0] * inv), f2bf(acc0[1] * inv), f2bf(acc0[2] * inv), f2bf(acc0[3] * inv) };
    us4 o1 = { f2bf(acc1[0] * inv), f2bf(acc1[1] * inv), f2bf(acc1[2] * inv), f2bf(acc1[3] * inv) };
    us4 o2 = { f2bf(acc2[0] * inv), f2bf(acc2[1] * inv), f2bf(acc2[2] * inv), f2bf(acc2[3] * inv) };
    us4 o3 = { f2bf(acc3[0] * inv), f2bf(acc3[1] * inv), f2bf(acc3[2] * inv), f2bf(acc3[3] * inv) };
    *(us4*)&O[ob + 0 * 16 + lg * 4] = o0;
    *(us4*)&O[ob + 1 * 16 + lg * 4] = o1;
    *(us4*)&O[ob + 2 * 16 + lg * 4] = o2;
    *(us4*)&O[ob + 3 * 16 + lg * 4] = o3;
  } else {
    if (lg == 0) pl[pidx] = psum;
    float* pb = &pacc[(size_t)pidx * 64];
    *(float4*)&pb[0 * 16 + lg * 4] = make_float4(acc0[0], acc0[1], acc0[2], acc0[3]);
    *(float4*)&pb[1 * 16 + lg * 4] = make_float4(acc1[0], acc1[1], acc1[2], acc1[3]);
    *(float4*)&pb[2 * 16 + lg * 4] = make_float4(acc2[0], acc2[1], acc2[2], acc2[3]);
    *(float4*)&pb[3 * 16 + lg * 4] = make_float4(acc3[0], acc3[1], acc3[2], acc3[3]);
  }
}

// ---------- merge 4 split-K partials -> attc bf16 (B,256,1024) ----------
__global__ __launch_bounds__(256) void k_fam(const float* __restrict__ pl0,
                                             const float* __restrict__ pacc0,
                                             unsigned short* __restrict__ attc) {
  int i = blockIdx.x * 256 + threadIdx.x;   // 131072 threads
  int row = i >> 4, d4 = (i & 15) << 2;
  float lsum = 0.f;
  float4 o = make_float4(0.f, 0.f, 0.f, 0.f);
#pragma unroll
  for (int s = 0; s < 4; ++s) {
    lsum += pl0[s * 8192 + row];
    float4 a = *(const float4*)&pacc0[((size_t)(s * 8192 + row)) * 64 + d4];
    o.x += a.x; o.y += a.y; o.z += a.z; o.w += a.w;
  }
  float inv = 1.f / lsum;
  int b = row >> 12, h = (row >> 8) & 15, q = row & 255;
  us4 ov = { f2bf(o.x * inv), f2bf(o.y * inv), f2bf(o.z * inv), f2bf(o.w * inv) };
  *(us4*)&attc[((size_t)(b * 256 + q)) * 1024 + h * 64 + d4] = ov;
}

extern "C" void kernel_launch(void* const* d_in, const int* in_sizes, int n_in,
                              void* d_out, int out_size, void* d_ws, size_t ws_size,
                              hipStream_t stream) {
  const float* x     = (const float*)d_in[0];
  const float* sq    = (const float*)d_in[1];
  const float* cq_w  = (const float*)d_in[2];
  const float* cq_b  = (const float*)d_in[3];
  const float* ck_w  = (const float*)d_in[4];
  const float* ck_b  = (const float*)d_in[5];
  const float* cv_w  = (const float*)d_in[6];
  const float* cv_b  = (const float*)d_in[7];
  const float* co_w  = (const float*)d_in[8];
  const float* co_b  = (const float*)d_in[9];
  const float* qkv_w = (const float*)d_in[10];
  const float* qkv_b = (const float*)d_in[11];
  const float* lo_w  = (const float*)d_in[12];
  const float* lo_b  = (const float*)d_in[13];
  float* out = (float*)d_out;

  char* ws = (char*)d_ws;
  size_t off = 0;
  auto alloc = [&](size_t bytes) -> void* {
    void* p = ws + off;
    off += (bytes + 255) & ~(size_t)255;
    return p;
  };
  unsigned short* xb    = (unsigned short*)alloc(16777216);  // x bf16 (B,4096,1024)
  unsigned short* sqb   = (unsigned short*)alloc(524288);
  unsigned short* cow16 = (unsigned short*)alloc(2097152);   // co_w bf16 row-major
  unsigned short* wqt   = (unsigned short*)alloc(2097152);
  unsigned short* wkvt  = (unsigned short*)alloc(4194304);   // [ck^T ; cv^T]
  unsigned short* wlot  = (unsigned short*)alloc(2097152);
  unsigned short* wqkvt = (unsigned short*)alloc(6291456);   // qkv^T (3072,1024)
  unsigned short* w2t   = (unsigned short*)alloc(4194304);   // (co_w @ qkv_w[:,1024:])^T
  float*          bias2 = (float*)alloc(8192);
  float*          kvb   = (float*)alloc(8192);
  float*          zbias = (float*)alloc(4096);
  float*          part  = (float*)alloc(131072);
  unsigned short* qs    = (unsigned short*)alloc(524288);    // summary q (256,1024)
  unsigned short* qx    = (unsigned short*)alloc(16777216);  // Q of x (B,4096,1024)
  unsigned short* kx    = (unsigned short*)alloc(16777216);  // K of x (B,4096,1024)
  unsigned short* vtx   = (unsigned short*)alloc(16777216);  // V^T of x (B,16,64,4096)
  unsigned short* gk    = (unsigned short*)alloc(1048576);   // gctx K (B,256,1024)
  unsigned short* gvt   = (unsigned short*)alloc(1048576);   // gctx V^T (B,16,64,256)
  unsigned short* kc    = (unsigned short*)alloc(4194304);   // comp K (B,1024,1024)
  unsigned short* vtc   = (unsigned short*)alloc(4194304);   // comp V^T (B,16,64,1024)
  unsigned short* attc  = (unsigned short*)alloc(1048576);   // comp attn out (B,256,1024)
  unsigned short* attl  = (unsigned short*)alloc(4194304);   // local attn out (B,1024,1024)
  unsigned short* cob   = (unsigned short*)alloc(4194304);   // chunk_out bf16
  float*          plb   = (float*)alloc(524288);             // (4,B,16,1024) l partials
  float*          pacc  = (float*)alloc(33554432);           // (4,B,16,1024,64) acc partials
  float*          pl0   = (float*)alloc(131072);             // (4,B,16,256) comp split-K l
  float*          pacc0 = (float*)alloc(8388608);            // (4,B,16,256,64) comp split-K acc

  // ---- prep (one fused dispatch) ----
  k_prep<<<16768, 256, 0, stream>>>(x, sq, co_w, xb, sqb, cow16,
                                    cq_w, ck_w, cv_w, lo_w, qkv_w,
                                    wqt, wkvt, wlot, wqkvt,
                                    qkv_w, co_b, part);
  k_bias2b<<<9, 256, 0, stream>>>(part, qkv_b, ck_b, cv_b, bias2, kvb, zbias);
  // q_summary
  k_gemm<64><<<dim3(4, 8), 128, 0, stream>>>(sqb, 0, 256, wqt, cq_b, qs, 1024, nullptr,
                                             nullptr, 0, 0, nullptr, nullptr, nullptr, 0, 1024, 1024);
  // W2^T
  k_gemm<128><<<dim3(16, 8), 256, 0, stream>>>(wqkvt + 1024 * 1024, 0, 2048, cow16, zbias,
                                               w2t, 1024, nullptr, nullptr, 0, 0,
                                               nullptr, nullptr, nullptr, 0, 1024, 1024);
  // big qkv projection: Q->qx, K->kx, V->vtx (BM=256: 768 blocks, 3/CU resident)
  k_gemm<256><<<dim3(32, 24), 512, 0, stream>>>(xb, 4096LL * 1024, 4096, wqkvt, qkv_b,
                                                qx, 1024, kx, vtx, 4096, 2048,
                                                nullptr, nullptr, nullptr, 0, 3072, 1024);
  // causal partials for ALL chunks (LPT-ordered grid)
  k_fa<1><<<2048, 256, 0, stream>>>(qx, 4096LL * 1024, 1024, 0,
                                    kx, 4096LL * 1024, 1024,
                                    vtx, 4096, nullptr, 0, plb, pacc);

  auto comp = [&](const unsigned short* inA, long long bsA) {
    k_gemm<64><<<dim3(32, 16), 128, 0, stream>>>(inA, bsA, 1024, wkvt, kvb,
                                                 kc, 1024, nullptr, vtc, 1024, 1024,
                                                 nullptr, nullptr, nullptr, 0, 2048, 1024);
    k_fa<3><<<512, 256, 0, stream>>>(qs, 0LL, 1024, 0,
                                     kc, 1024LL * 1024, 1024,
                                     vtc, 1024, nullptr, 0, pl0, pacc0);
    k_fam<<<512, 256, 0, stream>>>(pl0, pacc0, attc);
    k_gemm<64><<<dim3(8, 16), 128, 0, stream>>>(attc, 256LL * 1024, 256, w2t, bias2,
                                                gk, 1024, nullptr, gvt, 256, 1024,
                                                nullptr, nullptr, nullptr, 0, 2048, 1024);
  };

  comp(xb, 4096LL * 1024);  // gctx_0 from raw chunk 0
  for (int i = 0; i < 4; ++i) {
    k_fa<2><<<512, 256, 0, stream>>>(qx, 4096LL * 1024, 1024, i * 1024,
                                     gk, 256LL * 1024, 1024,
                                     gvt, 256, attl, 1024,
                                     plb + (size_t)i * 32768, pacc + (size_t)i * 32768 * 64);
    k_gemm<64><<<dim3(32, 8), 128, 0, stream>>>(attl, 1024LL * 1024, 1024, wlot, lo_b,
                                                nullptr, 1024, nullptr, nullptr, 0, 0,
                                                x, out, cob, i, 1024, 1024);
    if (i < 3) comp(cob, 1024LL * 1024);
  }
}